// Round 6
// baseline (296.125 us; speedup 1.0000x reference)
//
#include <hip/hip_runtime.h>

// ---------------------------------------------------------------------------
// Workspace layout (bytes):
//   idxb 0         : (2048,100) int        819200
//   sdn  819200    : (6,3,128) f32           9216
//   stp  828416    : 6 layers x 32 banks x 256 f32   196608
//   fo   1025024   : 3 x (2048,256) f32    6291456
//   p0.. 7316480   : 6 x (2048,128) f32    6291456   (end 13607936)
// ---------------------------------------------------------------------------

// ---------------------------------------------------------------------------
// GEMM body: out[r0..r0+31, 0..255] = bn_relu?(in rows) @ W(128x256) + bias.
// 256 threads: thread = 4 cols (cg=t&63) x 8 rows (rg=t>>6). W read once per
// 4 row-groups (x4 redundancy over 32 rows = 16KB/row through L1).
// stp: 32-bank partial sums (sum at [bank*256+c], sumsq at [bank*256+128+c]).
// ---------------------------------------------------------------------------
__device__ __forceinline__ void gemm_body(
    const float* __restrict__ in, const float* __restrict__ stp,
    const float* __restrict__ gm, const float* __restrict__ bt,
    const float* __restrict__ W, const float* __restrict__ bi,
    float* __restrict__ out, int rb, void* smem)
{
    float* rows  = (float*)smem;            // 32*128 = 16384 B
    float* scale = rows + 4096;             // 128
    float* shift = scale + 128;             // 128
    int t = threadIdx.x;
    if (t < 128) {
        float sc = 1.0f, sf = 0.0f;
        if (stp) {
            float sm = 0.0f, sq = 0.0f;
            for (int bk = 0; bk < 32; ++bk) {
                sm += stp[bk*256 + t];
                sq += stp[bk*256 + 128 + t];
            }
            float mu  = sm * (1.0f/2048.0f);
            float var = sq * (1.0f/2048.0f) - mu*mu;
            sc = rsqrtf(var + 1e-5f) * gm[t];
            sf = bt[t] - mu*sc;
        }
        scale[t] = sc; shift[t] = sf;
    }
    __syncthreads();
    int r0 = rb * 32;
    const float4* in4 = (const float4*)(in + r0*128);
    float4* rows4 = (float4*)rows;
    bool bn = (stp != 0);
    for (int q = t; q < 1024; q += 256) {
        float4 v = in4[q];
        if (bn) {
            int c4 = (q & 31) << 2;
            v.x = fmaxf(v.x*scale[c4  ] + shift[c4  ], 0.0f);
            v.y = fmaxf(v.y*scale[c4+1] + shift[c4+1], 0.0f);
            v.z = fmaxf(v.z*scale[c4+2] + shift[c4+2], 0.0f);
            v.w = fmaxf(v.w*scale[c4+3] + shift[c4+3], 0.0f);
        }
        rows4[q] = v;
    }
    __syncthreads();
    int cg = t & 63, rg = t >> 6;
    int rbase = rg * 8;
    float acc[8][4];
    #pragma unroll
    for (int r = 0; r < 8; ++r) { acc[r][0]=0.f; acc[r][1]=0.f; acc[r][2]=0.f; acc[r][3]=0.f; }
    const float4* W4 = (const float4*)W;
    for (int k = 0; k < 128; k += 4) {
        float4 a[8];
        #pragma unroll
        for (int r = 0; r < 8; ++r) a[r] = *(const float4*)&rows[(rbase+r)*128 + k];
        #pragma unroll
        for (int u = 0; u < 4; ++u) {
            float4 w = W4[(k+u)*64 + cg];
            #pragma unroll
            for (int r = 0; r < 8; ++r) {
                float av = (u==0) ? a[r].x : (u==1) ? a[r].y : (u==2) ? a[r].z : a[r].w;
                acc[r][0] += av*w.x; acc[r][1] += av*w.y;
                acc[r][2] += av*w.z; acc[r][3] += av*w.w;
            }
        }
    }
    float4 b4 = ((const float4*)bi)[cg];
    #pragma unroll
    for (int r = 0; r < 8; ++r) {
        float4 o;
        o.x = acc[r][0]+b4.x; o.y = acc[r][1]+b4.y;
        o.z = acc[r][2]+b4.z; o.w = acc[r][3]+b4.w;
        ((float4*)out)[(r0+rbase+r)*64 + cg] = o;
    }
}

// ---------------------------------------------------------------------------
// K1: fused knn (blocks 0..2047) + gemmA (2048..2239: 3 slots x 64) +
// zero stp (2240..2431). knn: radix-select 16-bit prefix of rank-101,
// compact superset, bitonic-256. Key=(sortable_dist<<32)|idx == top_k order.
// ---------------------------------------------------------------------------
__global__ void k1_kernel(const float* __restrict__ verts, const float* __restrict__ dirs,
                          const float* __restrict__ x,
                          const float* __restrict__ convW, const float* __restrict__ convB,
                          int* __restrict__ idxout, float* __restrict__ sdn,
                          float* __restrict__ stp, float* __restrict__ fo)
{
    __shared__ double smem[2336];          // 18688 B
    int t = threadIdx.x;
    int blk = blockIdx.x;

    if (blk >= 2240) {                     // zero stp: 192 blocks x 256 = 49152
        stp[(blk - 2240)*256 + t] = 0.0f;
        return;
    }
    if (blk >= 2048) {                     // gemmA: slots L0,L1,L3 (no input BN)
        int g = blk - 2048;
        int s = g >> 6, rb = g & 63;
        int wi = (s==0) ? 0 : (s==1) ? 1 : 3;
        gemm_body(x, (const float*)0, (const float*)0, (const float*)0,
                  convW + wi*32768, convB + wi*256, fo + s*524288, rb, smem);
        return;
    }

    // ---------------- knn ----------------
    float* sh = (float*)smem;                               // 4096 floats
    unsigned int* hist  = (unsigned int*)((char*)smem + 16384);
    unsigned int* scanb = (unsigned int*)((char*)smem + 17408);
    unsigned int* sel   = (unsigned int*)((char*)smem + 18432);
    unsigned long long* keys = (unsigned long long*)sh;

    int b = blk >> 10;
    int v = blk & 1023;
    const float* vb = verts + b * 3072;

    if (blk < 6 && t < 128) {              // fused dirs normalize
        float a = dirs[blk*384 + t];
        float bb = dirs[blk*384 + 128 + t];
        float c = dirs[blk*384 + 256 + t];
        float nrm = sqrtf(a*a + bb*bb + c*c);
        float inv = 1.0f / fmaxf(nrm, 1e-12f);
        sdn[blk*384 + t]       = a*inv;
        sdn[blk*384 + 128 + t] = bb*inv;
        sdn[blk*384 + 256 + t] = c*inv;
    }

    for (int j = t; j < 1024; j += 256) {
        float xx = vb[j*3+0], yy = vb[j*3+1], zz = vb[j*3+2];
        sh[j] = xx; sh[1024+j] = yy; sh[2048+j] = zz;
        sh[3072+j] = xx*xx + yy*yy + zz*zz;
    }
    __syncthreads();
    float cx = sh[v], cy = sh[1024+v], cz = sh[2048+v], csq = sh[3072+v];
    unsigned int du[4];
    unsigned long long kk[4];
    for (int q = 0; q < 4; ++q) {
        int j = t + 256*q;
        float dot = cx*sh[j] + cy*sh[1024+j] + cz*sh[2048+j];
        float d = -2.0f*dot + csq + sh[3072+j];
        unsigned int u = __float_as_uint(d);
        u = (u & 0x80000000u) ? ~u : (u | 0x80000000u);
        du[q] = u;
        kk[q] = (((unsigned long long)u) << 32) | (unsigned long long)j;
    }
    __syncthreads();

    hist[t] = 0; __syncthreads();
    for (int q = 0; q < 4; ++q) atomicAdd(&hist[du[q] >> 24], 1u);
    __syncthreads();
    scanb[t] = hist[t]; __syncthreads();
    for (int off = 1; off < 256; off <<= 1) {
        unsigned int add = (t >= off) ? scanb[t-off] : 0u;
        __syncthreads();
        scanb[t] += add;
        __syncthreads();
    }
    if (scanb[t] >= 101u && scanb[t] - hist[t] < 101u) {
        sel[0] = (unsigned int)t;
        sel[1] = 101u - (scanb[t] - hist[t]);
    }
    __syncthreads();
    unsigned int P8 = sel[0], rank2 = sel[1];

    __syncthreads();
    hist[t] = 0; __syncthreads();
    for (int q = 0; q < 4; ++q)
        if ((du[q] >> 24) == P8) atomicAdd(&hist[(du[q] >> 16) & 0xFFu], 1u);
    __syncthreads();
    scanb[t] = hist[t]; __syncthreads();
    for (int off = 1; off < 256; off <<= 1) {
        unsigned int add = (t >= off) ? scanb[t-off] : 0u;
        __syncthreads();
        scanb[t] += add;
        __syncthreads();
    }
    if (scanb[t] >= rank2 && scanb[t] - hist[t] < rank2) {
        sel[2] = (P8 << 8) | (unsigned int)t;
        sel[3] = 0u;
    }
    __syncthreads();
    unsigned int P16 = sel[2];

    for (int q = 0; q < 4; ++q) {
        if ((du[q] >> 16) <= P16) {
            unsigned int pos = atomicAdd(&sel[3], 1u);
            if (pos < 256u) keys[pos] = kk[q];
        }
    }
    __syncthreads();
    unsigned int cnt = sel[3];
    if ((unsigned int)t >= cnt) keys[t] = 0xFFFFFFFFFFFFFFFFULL;
    __syncthreads();

    for (int k = 2; k <= 256; k <<= 1) {
        for (int j = k >> 1; j > 0; j >>= 1) {
            int p = t ^ j;
            if (p > t) {
                bool up = ((t & k) == 0);
                unsigned long long a = keys[t], c = keys[p];
                if ((a > c) == up) { keys[t] = c; keys[p] = a; }
            }
            __syncthreads();
        }
    }
    if (t < 100)
        idxout[blk * 100 + t] = (int)(keys[t+1] & 0xFFFFFFFFu);
}

// ---------------------------------------------------------------------------
// Agg + fused BN-stat partials. blockIdx.x = row, blockIdx.y = slot.
// 128 threads = channels. Neighbor loop unrolled by 5 (5 | {5,20,100}) with
// batched independent gathers for latency hiding. Each block contributes its
// row to stp bank (r & 31) via 2 atomics/thread.
// ---------------------------------------------------------------------------
__global__ void agg_kernel(const int* __restrict__ idx, const float* __restrict__ verts,
                           const float* __restrict__ sdn, const float* __restrict__ fo,
                           int n0, int n1, int n2, int d0, int d1, int d2,
                           float* o0, float* o1, float* o2,
                           float* s0p, float* s1p, float* s2p)
{
    __shared__ float4 ds4[100];
    __shared__ int js[100];
    int slot = blockIdx.y;
    int n  = slot==0 ? n0 : slot==1 ? n1 : n2;
    int dI = slot==0 ? d0 : slot==1 ? d1 : d2;
    float* outp = slot==0 ? o0 : slot==1 ? o1 : o2;
    float* stp  = slot==0 ? s0p : slot==1 ? s1p : s2p;
    const float* fos = fo + slot * 524288;
    const float* sd = sdn + dI * 384;

    int r = blockIdx.x;
    int b = r >> 10;
    int t = threadIdx.x;
    if (t < n) {
        int j = idx[r*100 + t];
        js[t] = j;
        const float* pj = verts + (b*1024 + j)*3;
        const float* pv = verts + r*3;
        float dx = pj[0]-pv[0], dy = pj[1]-pv[1], dz = pj[2]-pv[2];
        float nm = sqrtf(dx*dx + dy*dy + dz*dz);
        float inv = 1.0f / fmaxf(nm, 1e-12f);
        ds4[t] = make_float4(dx*inv, dy*inv, dz*inv, 0.0f);
    }
    __syncthreads();
    float s0 = sd[t], s1 = sd[128+t], s2 = sd[256+t];
    int bb = b * 1024;
    float m = -3.0e38f;
    for (int q = 0; q < n; q += 5) {
        float th[5];
        const float* p[5];
        #pragma unroll
        for (int u = 0; u < 5; ++u) {
            float4 dq = ds4[q+u];
            th[u] = fmaxf(dq.x*s0 + dq.y*s1 + dq.z*s2, 0.0f);
            p[u] = fos + (size_t)(bb + js[q+u])*256 + 128 + t;
        }
        float vv[5];
        #pragma unroll
        for (int u = 0; u < 5; ++u) vv[u] = *p[u];
        #pragma unroll
        for (int u = 0; u < 5; ++u) m = fmaxf(m, th[u]*vv[u]);
    }
    float val = fos[r*256 + t] + m;
    outp[r*128 + t] = val;
    float* bank = stp + (r & 31)*256;
    atomicAdd(&bank[t], val);
    atomicAdd(&bank[128+t], val*val);
}

// ---------------------------------------------------------------------------
// Standalone gemm, up to 2 slots via blockIdx.y. grid (64, nslots), 256 thr.
// ---------------------------------------------------------------------------
__global__ void gemm2_kernel(
    const float* inA, const float* stpA, const float* gA, const float* beA,
    const float* WA, const float* biA, float* foA,
    const float* inB, const float* stpB, const float* gB, const float* beB,
    const float* WB, const float* biB, float* foB)
{
    __shared__ double smem[2336];
    if (blockIdx.y == 0)
        gemm_body(inA, stpA, gA, beA, WA, biA, foA, blockIdx.x, smem);
    else
        gemm_body(inB, stpB, gB, beB, WB, biB, foB, blockIdx.x, smem);
}

// ---------------------------------------------------------------------------
// Down-proj: row = [bn(p0)|bn(p1)|bn(p2)] (384) -> relu(row @ dW + db).
// 16 rows/block (128 blocks). Thread = 2 cols (cg=t&127) x 8 rows (rg=t>>7).
// ---------------------------------------------------------------------------
__global__ void down_kernel(
    const float* __restrict__ p0, const float* __restrict__ s0p,
    const float* __restrict__ g0, const float* __restrict__ be0,
    const float* __restrict__ p1, const float* __restrict__ s1p,
    const float* __restrict__ g1, const float* __restrict__ be1,
    const float* __restrict__ p2, const float* __restrict__ s2p,
    const float* __restrict__ g2, const float* __restrict__ be2,
    const float* __restrict__ dW, const float* __restrict__ db,
    float* __restrict__ out)
{
    __shared__ float rows[16*384];         // 24576 B
    __shared__ float scale[384], shift[384];
    int t = threadIdx.x;
    int r0 = blockIdx.x * 16;
    for (int c = t; c < 384; c += 256) {
        int seg = c >> 7, cc = c & 127;
        const float* stp = seg==0 ? s0p : seg==1 ? s1p : s2p;
        const float* g   = seg==0 ? g0  : seg==1 ? g1  : g2;
        const float* be  = seg==0 ? be0 : seg==1 ? be1 : be2;
        float sm = 0.0f, sq = 0.0f;
        for (int bk = 0; bk < 32; ++bk) {
            sm += stp[bk*256 + cc];
            sq += stp[bk*256 + 128 + cc];
        }
        float mu  = sm * (1.0f/2048.0f);
        float var = sq * (1.0f/2048.0f) - mu*mu;
        float s = rsqrtf(var + 1e-5f) * g[cc];
        scale[c] = s;
        shift[c] = be[cc] - mu*s;
    }
    __syncthreads();
    #pragma unroll
    for (int seg = 0; seg < 3; ++seg) {
        const float* ps = seg==0 ? p0 : seg==1 ? p1 : p2;
        const float4* ps4 = (const float4*)(ps + r0*128);
        for (int q = t; q < 512; q += 256) {
            int row = q >> 5, c4 = (q & 31) << 2;
            float4 v = ps4[q];
            int sc = seg*128 + c4;
            v.x = fmaxf(v.x*scale[sc  ] + shift[sc  ], 0.0f);
            v.y = fmaxf(v.y*scale[sc+1] + shift[sc+1], 0.0f);
            v.z = fmaxf(v.z*scale[sc+2] + shift[sc+2], 0.0f);
            v.w = fmaxf(v.w*scale[sc+3] + shift[sc+3], 0.0f);
            *(float4*)&rows[row*384 + sc] = v;
        }
    }
    __syncthreads();
    int cg = t & 127, rg = t >> 7;
    int rbase = rg * 8;
    float acc[8][2];
    #pragma unroll
    for (int r = 0; r < 8; ++r) { acc[r][0] = 0.f; acc[r][1] = 0.f; }
    const float2* W2 = (const float2*)dW;
    for (int k = 0; k < 384; k += 4) {
        float4 a[8];
        #pragma unroll
        for (int r = 0; r < 8; ++r) a[r] = *(const float4*)&rows[(rbase+r)*384 + k];
        #pragma unroll
        for (int u = 0; u < 4; ++u) {
            float2 w = W2[(k+u)*128 + cg];
            #pragma unroll
            for (int r = 0; r < 8; ++r) {
                float av = (u==0) ? a[r].x : (u==1) ? a[r].y : (u==2) ? a[r].z : a[r].w;
                acc[r][0] += av*w.x; acc[r][1] += av*w.y;
            }
        }
    }
    float2 b2 = ((const float2*)db)[cg];
    #pragma unroll
    for (int r = 0; r < 8; ++r) {
        float2 o;
        o.x = fmaxf(acc[r][0] + b2.x, 0.0f);
        o.y = fmaxf(acc[r][1] + b2.y, 0.0f);
        ((float2*)out)[(r0+rbase+r)*128 + cg] = o;
    }
}

// ---------------------------------------------------------------------------
extern "C" void kernel_launch(void* const* d_in, const int* in_sizes, int n_in,
                              void* d_out, int out_size, void* d_ws, size_t ws_size,
                              hipStream_t stream)
{
    (void)in_sizes; (void)n_in; (void)out_size; (void)ws_size;
    const float* verts = (const float*)d_in[0];
    const float* x     = (const float*)d_in[1];
    const float* convW = (const float*)d_in[2];
    const float* convB = (const float*)d_in[3];
    const float* dirs  = (const float*)d_in[4];
    const float* gam   = (const float*)d_in[5];
    const float* bet   = (const float*)d_in[6];
    const float* dW    = (const float*)d_in[7];
    const float* db    = (const float*)d_in[8];
    float* out = (float*)d_out;

    char* ws = (char*)d_ws;
    int*   idxb = (int*)(ws);
    float* sdn  = (float*)(ws + 819200);
    float* stp  = (float*)(ws + 828416);     // 6 x 32 x 256 f32
    float* fo   = (float*)(ws + 1025024);    // 3 x (2048,256)
    float* p0   = (float*)(ws + 7316480);
    float* p1   = (float*)(ws + 8365056);
    float* p2   = (float*)(ws + 9413632);
    float* p3   = (float*)(ws + 10462208);
    float* p4   = (float*)(ws + 11510784);
    float* p5   = (float*)(ws + 12559360);

    const float* nf = (const float*)0;
    float* nw = (float*)0;
    float* stL0 = stp,          *stL1 = stp + 8192, *stL2 = stp + 16384;
    float* stL3 = stp + 24576,  *stL4 = stp + 32768, *stL5 = stp + 40960;

    // K1: knn + gemmA (L0,L1,L3 from x) + zero stp
    k1_kernel<<<2432, 256, 0, stream>>>(verts, dirs, x, convW, convB,
                                        idxb, sdn, stp, fo);
    // K2: aggA -> p0/p1/p3 (+stat partials)
    agg_kernel<<<dim3(2048,3), 128, 0, stream>>>(
        idxb, verts, sdn, fo, 5, 20, 100, 0, 1, 3,
        p0, p1, p3, stL0, stL1, stL3);
    // K3: gemmB: L2 from bn(p1,st1,g1,b1); L4 from bn(p3,st3,g3,b3)
    gemm2_kernel<<<dim3(64,2), 256, 0, stream>>>(
        p1, stL1, gam + 128, bet + 128, convW + 65536,  convB + 512,  fo,
        p3, stL3, gam + 384, bet + 384, convW + 131072, convB + 1024, fo + 524288);
    // K4: aggB -> p2/p4
    agg_kernel<<<dim3(2048,2), 128, 0, stream>>>(
        idxb, verts, sdn, fo, 20, 100, 0, 2, 4, 0,
        p2, p4, nw, stL2, stL4, nw);
    // K5: gemmC: L5-conv (params3) from bn(p4,st4,g4,b4)
    gemm2_kernel<<<dim3(64,1), 256, 0, stream>>>(
        p4, stL4, gam + 512, bet + 512, convW + 98304, convB + 768, fo,
        nf, nf, nf, nf, nf, nf, nw);
    // K6: aggC -> p5 (dirs idx 3)
    agg_kernel<<<dim3(2048,1), 128, 0, stream>>>(
        idxb, verts, sdn, fo, 100, 0, 0, 3, 0, 0,
        p5, nw, nw, stL5, nw, nw);
    // K7: down: bn(p0,st0,g0,b0) | bn(p2,st2,g2,b2) | bn(p5,st5,g3,b3)
    down_kernel<<<128, 256, 0, stream>>>(
        p0, stL0, gam, bet,
        p2, stL2, gam + 256, bet + 256,
        p5, stL5, gam + 384, bet + 384,
        dW, db, out);
}